// Round 1
// baseline (397.802 us; speedup 1.0000x reference)
//
#include <hip/hip_runtime.h>

#define NWIN   8192
#define NTOK   49
#define CDIM   128
#define NHEAD  4
#define HDIM   32

typedef __attribute__((ext_vector_type(8))) short bf16x8;
typedef __attribute__((ext_vector_type(4))) float f32x4;

__device__ __forceinline__ unsigned short f2bf(float f) {
  union { float f; unsigned int u; } v; v.f = f;
  unsigned int r = v.u + 0x7FFFu + ((v.u >> 16) & 1u);
  return (unsigned short)(r >> 16);
}

// ---------------- prep: weights -> bf16, bias -> MFMA fragment layout ----------------
__global__ void swin_prep(const float* __restrict__ qkv_w,
                          const float* __restrict__ out_w,
                          const float* __restrict__ bias_table,
                          const int* __restrict__ rel_idx,
                          unsigned short* __restrict__ wqkv,
                          unsigned short* __restrict__ wout,
                          float* __restrict__ biasf) {
  int idx = blockIdx.x * 256 + threadIdx.x;
  if (idx < 3 * CDIM * CDIM) wqkv[idx] = f2bf(qkv_w[idx]);
  if (idx < CDIM * CDIM) wout[idx] = f2bf(out_w[idx]);
  // biasf[h][i][j][lane][reg] = bias[h][n][m], n = i*16+(lane>>4)*4+reg, m = j*16+(lane&15)
  if (idx < NHEAD * 4 * 4 * 64 * 4) {
    int r    = idx & 3;
    int lane = (idx >> 2) & 63;
    int j    = (idx >> 8) & 3;
    int i    = (idx >> 10) & 3;
    int h    = (idx >> 12);
    int n = i * 16 + (lane >> 4) * 4 + r;
    int m = j * 16 + (lane & 15);
    float v = 0.f;
    if (n < NTOK && m < NTOK)
      v = bias_table[rel_idx[n * NTOK + m] * NHEAD + h];
    biasf[idx] = v;
  }
}

// ---------------- fused swin window attention: 1 wave = 1 window ----------------
// LDS per wave (ushorts): U[0..5120) = union{ Q[64][40] @0 | K[64][40] @2560 |
//                                             P[64][72] @0 | AO[64][40] @0 }
//                         Vt[32][72] @5120   -> 7424 ushorts = 14,848 B/wave
__global__ __launch_bounds__(256, 2) void swin_fused(
    const float* __restrict__ x,
    const unsigned short* __restrict__ wqkv,
    const float* __restrict__ bqkv,
    const unsigned short* __restrict__ wout,
    const float* __restrict__ bout,
    const float* __restrict__ biasf,
    float* __restrict__ out)
{
  __shared__ unsigned short lds[4][7424];
  const int tid  = threadIdx.x;
  const int w    = tid >> 6;
  const int lane = tid & 63;
  const int l15  = lane & 15;
  const int lg   = lane >> 4;
  const int win  = blockIdx.x * 4 + w;

  unsigned short* U   = lds[w];
  unsigned short* Qb  = U;           // [64][40]
  unsigned short* Kb  = U + 2560;    // [64][40]
  unsigned short* Pb  = U;           // [64][72] (overlay, after Q/K consumed)
  unsigned short* AOb = U;           // [64][40] (overlay, after P consumed)
  unsigned short* Vt  = U + 5120;    // [32][72]

  const float* xw = x + (size_t)win * (NTOK * CDIM);

  // ---- X A-fragments in registers: xa[i][kk], row = i*16+l15 (clamped), k = kk*32+lg*8 ----
  bf16x8 xa[4][4];
  #pragma unroll
  for (int i = 0; i < 4; ++i) {
    int row = i * 16 + l15; row = row > 48 ? 48 : row;   // clamp ragged pad (finite garbage)
    const float* xr = xw + row * CDIM + lg * 8;
    #pragma unroll
    for (int kk = 0; kk < 4; ++kk) {
      float4 a = *reinterpret_cast<const float4*>(xr + kk * 32);
      float4 b = *reinterpret_cast<const float4*>(xr + kk * 32 + 4);
      union { bf16x8 v; unsigned short u[8]; } t;
      t.u[0] = f2bf(a.x); t.u[1] = f2bf(a.y); t.u[2] = f2bf(a.z); t.u[3] = f2bf(a.w);
      t.u[4] = f2bf(b.x); t.u[5] = f2bf(b.y); t.u[6] = f2bf(b.z); t.u[7] = f2bf(b.w);
      xa[i][kk] = t.v;
    }
  }

  const float scale = 0.17677669529663687f;  // 32^-0.5
  const f32x4 fz = {0.f, 0.f, 0.f, 0.f};

  f32x4 pacc[4][8];
  #pragma unroll
  for (int i = 0; i < 4; ++i)
    #pragma unroll
    for (int j = 0; j < 8; ++j) pacc[i][j] = fz;

  for (int h = 0; h < NHEAD; ++h) {
    // ================= QKV projection (N = 6 tiles of 16: Q0 Q1 K0 K1 V0 V1) =================
    #pragma unroll
    for (int nt = 0; nt < 6; ++nt) {
      const int s = nt >> 1, t = nt & 1;
      const int colbase = s * CDIM + h * HDIM + t * 16;
      const unsigned short* wr = wqkv + (colbase + l15) * CDIM + lg * 8;
      bf16x8 wb[4];
      #pragma unroll
      for (int kk = 0; kk < 4; ++kk)
        wb[kk] = *reinterpret_cast<const bf16x8*>(wr + kk * 32);
      f32x4 acc[4];
      #pragma unroll
      for (int i = 0; i < 4; ++i) acc[i] = fz;
      #pragma unroll
      for (int kk = 0; kk < 4; ++kk)
        #pragma unroll
        for (int i = 0; i < 4; ++i)
          acc[i] = __builtin_amdgcn_mfma_f32_16x16x32_bf16(xa[i][kk], wb[kk], acc[i], 0, 0, 0);
      const float bias = bqkv[colbase + l15];
      #pragma unroll
      for (int i = 0; i < 4; ++i) {
        #pragma unroll
        for (int r = 0; r < 4; ++r) {
          float v = acc[i][r] + bias;
          int row = i * 16 + lg * 4 + r;   // token index
          if (s == 0)      Qb[row * 40 + t * 16 + l15] = f2bf(v * scale);
          else if (s == 1) Kb[row * 40 + t * 16 + l15] = f2bf(v);
          else             Vt[(t * 16 + l15) * 72 + row] = f2bf(v);  // transposed V
        }
      }
    }

    // ================= S = Q K^T + bias, softmax -> P (bf16 in LDS) =================
    bf16x8 qa[4], kb[4];
    #pragma unroll
    for (int j = 0; j < 4; ++j)
      kb[j] = *reinterpret_cast<const bf16x8*>(Kb + (j * 16 + l15) * 40 + lg * 8);
    #pragma unroll
    for (int i = 0; i < 4; ++i)
      qa[i] = *reinterpret_cast<const bf16x8*>(Qb + (i * 16 + l15) * 40 + lg * 8);

    #pragma unroll
    for (int i = 0; i < 4; ++i) {
      f32x4 sj[4];
      #pragma unroll
      for (int j = 0; j < 4; ++j)
        sj[j] = __builtin_amdgcn_mfma_f32_16x16x32_bf16(qa[i], kb[j], fz, 0, 0, 0);
      #pragma unroll
      for (int j = 0; j < 4; ++j) {
        float4 bf = *reinterpret_cast<const float4*>(
            biasf + ((((h * 4 + i) * 4 + j) * 64 + lane) * 4));
        sj[j][0] += bf.x; sj[j][1] += bf.y; sj[j][2] += bf.z; sj[j][3] += bf.w;
      }
      if (l15 != 0) { sj[3][0] = -1e30f; sj[3][1] = -1e30f; sj[3][2] = -1e30f; sj[3][3] = -1e30f; }

      float mx[4], sm[4];
      #pragma unroll
      for (int r = 0; r < 4; ++r)
        mx[r] = fmaxf(fmaxf(sj[0][r], sj[1][r]), fmaxf(sj[2][r], sj[3][r]));
      #pragma unroll
      for (int r = 0; r < 4; ++r) {
        mx[r] = fmaxf(mx[r], __shfl_xor(mx[r], 1));
        mx[r] = fmaxf(mx[r], __shfl_xor(mx[r], 2));
        mx[r] = fmaxf(mx[r], __shfl_xor(mx[r], 4));
        mx[r] = fmaxf(mx[r], __shfl_xor(mx[r], 8));
      }
      #pragma unroll
      for (int r = 0; r < 4; ++r) sm[r] = 0.f;
      #pragma unroll
      for (int j = 0; j < 4; ++j)
        #pragma unroll
        for (int r = 0; r < 4; ++r) {
          float p = __expf(sj[j][r] - mx[r]);
          sj[j][r] = p; sm[r] += p;
        }
      #pragma unroll
      for (int r = 0; r < 4; ++r) {
        sm[r] += __shfl_xor(sm[r], 1);
        sm[r] += __shfl_xor(sm[r], 2);
        sm[r] += __shfl_xor(sm[r], 4);
        sm[r] += __shfl_xor(sm[r], 8);
        sm[r] = 1.f / sm[r];
      }
      #pragma unroll
      for (int j = 0; j < 4; ++j)
        #pragma unroll
        for (int r = 0; r < 4; ++r)
          Pb[(i * 16 + lg * 4 + r) * 72 + j * 16 + l15] = f2bf(sj[j][r] * sm[r]);
    }

    // ================= O = P V =================
    f32x4 o[4][2];
    #pragma unroll
    for (int i = 0; i < 4; ++i) { o[i][0] = fz; o[i][1] = fz; }
    #pragma unroll
    for (int kk2 = 0; kk2 < 2; ++kk2) {
      bf16x8 vb0 = *reinterpret_cast<const bf16x8*>(Vt + (l15)      * 72 + kk2 * 32 + lg * 8);
      bf16x8 vb1 = *reinterpret_cast<const bf16x8*>(Vt + (16 + l15) * 72 + kk2 * 32 + lg * 8);
      #pragma unroll
      for (int i = 0; i < 4; ++i) {
        bf16x8 pa = *reinterpret_cast<const bf16x8*>(Pb + (i * 16 + l15) * 72 + kk2 * 32 + lg * 8);
        o[i][0] = __builtin_amdgcn_mfma_f32_16x16x32_bf16(pa, vb0, o[i][0], 0, 0, 0);
        o[i][1] = __builtin_amdgcn_mfma_f32_16x16x32_bf16(pa, vb1, o[i][1], 0, 0, 0);
      }
    }

    // ================= AO -> LDS (transpose), partial out-projection =================
    #pragma unroll
    for (int i = 0; i < 4; ++i)
      #pragma unroll
      for (int t = 0; t < 2; ++t)
        #pragma unroll
        for (int r = 0; r < 4; ++r)
          AOb[(i * 16 + lg * 4 + r) * 40 + t * 16 + l15] = f2bf(o[i][t][r]);

    bf16x8 ab[4];
    #pragma unroll
    for (int i = 0; i < 4; ++i)
      ab[i] = *reinterpret_cast<const bf16x8*>(AOb + (i * 16 + l15) * 40 + lg * 8);
    #pragma unroll
    for (int j = 0; j < 8; ++j) {
      bf16x8 wb2 = *reinterpret_cast<const bf16x8*>(wout + (j * 16 + l15) * CDIM + h * HDIM + lg * 8);
      #pragma unroll
      for (int i = 0; i < 4; ++i)
        pacc[i][j] = __builtin_amdgcn_mfma_f32_16x16x32_bf16(ab[i], wb2, pacc[i][j], 0, 0, 0);
    }
  }

  // ================= store =================
  float* ow = out + (size_t)win * (NTOK * CDIM);
  #pragma unroll
  for (int j = 0; j < 8; ++j) {
    const float ob = bout[j * 16 + l15];
    #pragma unroll
    for (int i = 0; i < 4; ++i)
      #pragma unroll
      for (int r = 0; r < 4; ++r) {
        int n = i * 16 + lg * 4 + r;
        if (n < NTOK) ow[n * CDIM + j * 16 + l15] = pacc[i][j][r] + ob;
      }
  }
}

extern "C" void kernel_launch(void* const* d_in, const int* in_sizes, int n_in,
                              void* d_out, int out_size, void* d_ws, size_t ws_size,
                              hipStream_t stream) {
  (void)in_sizes; (void)n_in; (void)out_size; (void)ws_size;
  const float* x          = (const float*)d_in[0];
  const float* qkv_w      = (const float*)d_in[1];
  const float* qkv_b      = (const float*)d_in[2];
  const float* out_w      = (const float*)d_in[3];
  const float* out_b      = (const float*)d_in[4];
  const float* bias_table = (const float*)d_in[5];
  const int*   rel_idx    = (const int*)d_in[6];
  float* out = (float*)d_out;

  unsigned short* wqkv = (unsigned short*)d_ws;                      // 98,304 B
  unsigned short* wout = wqkv + 3 * CDIM * CDIM;                     // 32,768 B
  float* biasf = (float*)((char*)d_ws + 131072);                     // 65,536 B

  swin_prep<<<192, 256, 0, stream>>>(qkv_w, out_w, bias_table, rel_idx, wqkv, wout, biasf);
  swin_fused<<<NWIN / 4, 256, 0, stream>>>(x, wqkv, qkv_b, wout, out_b, biasf, out);
}

// Round 2
// 216.079 us; speedup vs baseline: 1.8410x; 1.8410x over previous
//
#include <hip/hip_runtime.h>

#define NWIN   8192
#define NTOK   49
#define CDIM   128
#define NHEAD  4
#define HDIM   32

typedef __attribute__((ext_vector_type(8))) short bf16x8;
typedef __attribute__((ext_vector_type(4))) float f32x4;

#define MFMA __builtin_amdgcn_mfma_f32_16x16x32_bf16

__device__ __forceinline__ unsigned short f2bf(float f) {
  union { float f; unsigned int u; } v; v.f = f;
  unsigned int r = v.u + 0x7FFFu + ((v.u >> 16) & 1u);
  return (unsigned short)(r >> 16);
}

// pack two f32 -> one dword of 2 bf16 (RNE), single instruction
__device__ __forceinline__ int cvtpk(float lo, float hi) {
  int r;
  asm("v_cvt_pk_bf16_f32 %0, %1, %2" : "=v"(r) : "v"(lo), "v"(hi));
  return r;
}

// ---------------- prep: weights -> bf16 (Q rows pre-scaled), bias -> S^T fragment layout ----------------
__global__ void swin_prep(const float* __restrict__ qkv_w,
                          const float* __restrict__ out_w,
                          const float* __restrict__ bias_table,
                          const int* __restrict__ rel_idx,
                          unsigned short* __restrict__ wqkv,
                          unsigned short* __restrict__ wout,
                          float* __restrict__ biasf) {
  int idx = blockIdx.x * 256 + threadIdx.x;
  if (idx < 3 * CDIM * CDIM) {
    float v = qkv_w[idx];
    if (idx < CDIM * CDIM) v *= 0.17677669529663687f;   // fold QK scale into Q weights
    wqkv[idx] = f2bf(v);
  }
  if (idx < CDIM * CDIM) wout[idx] = f2bf(out_w[idx]);
  // S^T layout: biasf[h][i][j][lane][r] = bias[h][n][m], n = i*16+(lane&15), m = j*16+(lane>>4)*4+r
  if (idx < NHEAD * 4 * 4 * 64 * 4) {
    int r    = idx & 3;
    int lane = (idx >> 2) & 63;
    int j    = (idx >> 8) & 3;
    int i    = (idx >> 10) & 3;
    int h    = (idx >> 12);
    int n = i * 16 + (lane & 15);
    int m = j * 16 + (lane >> 4) * 4 + r;
    float v = 0.f;
    if (n < NTOK && m < NTOK)
      v = bias_table[rel_idx[n * NTOK + m] * NHEAD + h];
    biasf[idx] = v;
  }
}

// ---------------- fused, fully register-resident (ZERO LDS): 1 wave = 1 window ----------------
__global__ __launch_bounds__(256) void swin_fused(
    const float* __restrict__ x,
    const unsigned short* __restrict__ wqkv,
    const float* __restrict__ bqkv,
    const unsigned short* __restrict__ wout,
    const float* __restrict__ bout,
    const float* __restrict__ biasf,
    float* __restrict__ out)
{
  const int lane = threadIdx.x & 63;
  const int l15  = lane & 15;
  const int lg   = lane >> 4;
  const int win  = blockIdx.x * 4 + (threadIdx.x >> 6);

  // lane-exchange sources: partners sharing l15 (C/D "reg rows" -> frag "k-chunks")
  const int srcA = l15 + 32 * (lg & 1);
  const int srcB = srcA + 16;
  const bool sel = ((lg >> 1) & 1) != 0;

  const f32x4 fz = {0.f, 0.f, 0.f, 0.f};

  // exchange: inputs are (even-tile dw0,dw1, odd-tile dw0,dw1) held per lane in C/D
  // packing; output is the bf16x8 A/B fragment (k = lg*8+e over the 32-wide pair).
  #define XCHG(res, e0, e1, o0, o1)                                   \
    {                                                                  \
      int a0 = __shfl((e0), srcA, 64), b0 = __shfl((o0), srcA, 64);    \
      int a1 = __shfl((e1), srcA, 64), b1 = __shfl((o1), srcA, 64);    \
      int a2 = __shfl((e0), srcB, 64), b2 = __shfl((o0), srcB, 64);    \
      int a3 = __shfl((e1), srcB, 64), b3 = __shfl((o1), srcB, 64);    \
      union { int w[4]; bf16x8 v; } ux;                                \
      ux.w[0] = sel ? b0 : a0;                                         \
      ux.w[1] = sel ? b1 : a1;                                         \
      ux.w[2] = sel ? b2 : a2;                                         \
      ux.w[3] = sel ? b3 : a3;                                         \
      res = ux.v;                                                      \
    }

  // ---- X A-fragments in registers: xa[i][kk]: row n = i*16+l15 (clamped), k = kk*32+lg*8 ----
  bf16x8 xa[4][4];
  const float* xw = x + (size_t)win * (NTOK * CDIM);
  #pragma unroll
  for (int i = 0; i < 4; ++i) {
    int row = i * 16 + l15; row = row > 48 ? 48 : row;   // ragged pad: finite duplicates
    const float* xr = xw + row * CDIM + lg * 8;
    #pragma unroll
    for (int kk = 0; kk < 4; ++kk) {
      float4 a = *reinterpret_cast<const float4*>(xr + kk * 32);
      float4 b = *reinterpret_cast<const float4*>(xr + kk * 32 + 4);
      union { int w[4]; bf16x8 v; } t;
      t.w[0] = cvtpk(a.x, a.y); t.w[1] = cvtpk(a.z, a.w);
      t.w[2] = cvtpk(b.x, b.y); t.w[3] = cvtpk(b.z, b.w);
      xa[i][kk] = t.v;
    }
  }

  bf16x8 af[4][4];   // [h][i] out-projection A-frags (n on l15, k = d in head)

  #pragma unroll
  for (int h = 0; h < NHEAD; ++h) {
    // ================= V projection (token on reg, d on l15) -> vf B-frags =================
    int dwV[2][4][2];
    #pragma unroll
    for (int t = 0; t < 2; ++t) {
      const unsigned short* wr = wqkv + (size_t)(2 * CDIM + h * HDIM + t * 16 + l15) * CDIM + lg * 8;
      bf16x8 wb[4];
      #pragma unroll
      for (int kk = 0; kk < 4; ++kk) wb[kk] = *reinterpret_cast<const bf16x8*>(wr + kk * 32);
      const float bv = bqkv[2 * CDIM + h * HDIM + t * 16 + l15];
      #pragma unroll
      for (int i = 0; i < 4; ++i) {
        f32x4 acc = fz;
        #pragma unroll
        for (int kk = 0; kk < 4; ++kk) acc = MFMA(xa[i][kk], wb[kk], acc, 0, 0, 0);
        dwV[t][i][0] = cvtpk(acc[0] + bv, acc[1] + bv);
        dwV[t][i][1] = cvtpk(acc[2] + bv, acc[3] + bv);
      }
    }
    bf16x8 vf[2][2];   // (d on l15, k = token m chunk kk2)
    #pragma unroll
    for (int t = 0; t < 2; ++t)
      #pragma unroll
      for (int kk2 = 0; kk2 < 2; ++kk2)
        XCHG(vf[t][kk2], dwV[t][kk2 * 2][0], dwV[t][kk2 * 2][1],
                          dwV[t][kk2 * 2 + 1][0], dwV[t][kk2 * 2 + 1][1]);

    // ================= Q,K transposed projection (c on reg, token on l15) -> frags =================
    bf16x8 qf[4], kf[4];
    #pragma unroll
    for (int s = 0; s < 2; ++s) {
      int dwQ[2][4][2];
      #pragma unroll
      for (int t = 0; t < 2; ++t) {
        const int colbase = s * CDIM + h * HDIM + t * 16;
        const unsigned short* wr = wqkv + (size_t)(colbase + l15) * CDIM + lg * 8;
        bf16x8 wb[4];
        #pragma unroll
        for (int kk = 0; kk < 4; ++kk) wb[kk] = *reinterpret_cast<const bf16x8*>(wr + kk * 32);
        float4 b4 = *reinterpret_cast<const float4*>(bqkv + colbase + lg * 4);
        if (s == 0) { b4.x *= 0.17677669529663687f; b4.y *= 0.17677669529663687f;
                      b4.z *= 0.17677669529663687f; b4.w *= 0.17677669529663687f; }
        #pragma unroll
        for (int i = 0; i < 4; ++i) {
          f32x4 acc = fz;
          #pragma unroll
          for (int kk = 0; kk < 4; ++kk) acc = MFMA(wb[kk], xa[i][kk], acc, 0, 0, 0);
          dwQ[t][i][0] = cvtpk(acc[0] + b4.x, acc[1] + b4.y);
          dwQ[t][i][1] = cvtpk(acc[2] + b4.z, acc[3] + b4.w);
        }
      }
      #pragma unroll
      for (int i = 0; i < 4; ++i) {
        bf16x8 f;
        XCHG(f, dwQ[0][i][0], dwQ[0][i][1], dwQ[1][i][0], dwQ[1][i][1]);
        if (s == 0) qf[i] = f; else kf[i] = f;
      }
    }

    // ================= per q-tile: S^T = K Q^T, softmax, O^T = V^T P^T =================
    #pragma unroll
    for (int i = 0; i < 4; ++i) {
      f32x4 sj[4];
      #pragma unroll
      for (int j = 0; j < 4; ++j) sj[j] = MFMA(kf[j], qf[i], fz, 0, 0, 0);
      #pragma unroll
      for (int j = 0; j < 4; ++j) {
        float4 bb = *reinterpret_cast<const float4*>(
            biasf + ((((h * 4 + i) * 4 + j) * 64 + lane) * 4));
        sj[j][0] += bb.x; sj[j][1] += bb.y; sj[j][2] += bb.z; sj[j][3] += bb.w;
      }
      // mask m > 48: j==3 holds m = 48 + lg*4 + r -> only (lg==0, r==0) valid
      sj[3][0] = (lg == 0) ? sj[3][0] : -1e30f;
      sj[3][1] = -1e30f; sj[3][2] = -1e30f; sj[3][3] = -1e30f;

      // softmax over the row (16 local values + lanes l15,l15+16,+32,+48)
      float mx = sj[0][0];
      #pragma unroll
      for (int j = 0; j < 4; ++j)
        #pragma unroll
        for (int r = 0; r < 4; ++r) mx = fmaxf(mx, sj[j][r]);
      mx = fmaxf(mx, __shfl_xor(mx, 16, 64));
      mx = fmaxf(mx, __shfl_xor(mx, 32, 64));
      float sm = 0.f;
      #pragma unroll
      for (int j = 0; j < 4; ++j)
        #pragma unroll
        for (int r = 0; r < 4; ++r) {
          float p = __expf(sj[j][r] - mx);
          sj[j][r] = p; sm += p;
        }
      sm += __shfl_xor(sm, 16, 64);
      sm += __shfl_xor(sm, 32, 64);
      const float inv = 1.f / sm;

      int dwP[4][2];
      #pragma unroll
      for (int j = 0; j < 4; ++j) {
        dwP[j][0] = cvtpk(sj[j][0] * inv, sj[j][1] * inv);
        dwP[j][1] = cvtpk(sj[j][2] * inv, sj[j][3] * inv);
      }
      bf16x8 pa0, pa1;
      XCHG(pa0, dwP[0][0], dwP[0][1], dwP[1][0], dwP[1][1]);
      XCHG(pa1, dwP[2][0], dwP[2][1], dwP[3][0], dwP[3][1]);

      // O^T = V^T * P^T : (d on reg, n on l15)
      f32x4 o0 = MFMA(vf[0][0], pa0, fz, 0, 0, 0);
      o0 = MFMA(vf[0][1], pa1, o0, 0, 0, 0);
      f32x4 o1 = MFMA(vf[1][0], pa0, fz, 0, 0, 0);
      o1 = MFMA(vf[1][1], pa1, o1, 0, 0, 0);

      int a00 = cvtpk(o0[0], o0[1]), a01 = cvtpk(o0[2], o0[3]);
      int a10 = cvtpk(o1[0], o1[1]), a11 = cvtpk(o1[2], o1[3]);
      XCHG(af[h][i], a00, a01, a10, a11);
    }
  }

  // ================= out projection: OUT = AO * Wout^T (K=128 over 4 heads) =================
  float* ow = out + (size_t)win * (NTOK * CDIM);
  #pragma unroll
  for (int j = 0; j < 8; ++j) {
    bf16x8 wb2[4];
    #pragma unroll
    for (int h = 0; h < 4; ++h)
      wb2[h] = *reinterpret_cast<const bf16x8*>(wout + (size_t)(j * 16 + l15) * CDIM + h * HDIM + lg * 8);
    f32x4 acc[4];
    #pragma unroll
    for (int i = 0; i < 4; ++i) acc[i] = fz;
    #pragma unroll
    for (int h = 0; h < 4; ++h)
      #pragma unroll
      for (int i = 0; i < 4; ++i)
        acc[i] = MFMA(af[h][i], wb2[h], acc[i], 0, 0, 0);
    const float ob = bout[j * 16 + l15];
    #pragma unroll
    for (int i = 0; i < 4; ++i)
      #pragma unroll
      for (int r = 0; r < 4; ++r) {
        int n = i * 16 + lg * 4 + r;
        if (n < NTOK) ow[n * CDIM + j * 16 + l15] = acc[i][r] + ob;
      }
  }
  #undef XCHG
}

extern "C" void kernel_launch(void* const* d_in, const int* in_sizes, int n_in,
                              void* d_out, int out_size, void* d_ws, size_t ws_size,
                              hipStream_t stream) {
  (void)in_sizes; (void)n_in; (void)out_size; (void)ws_size;
  const float* x          = (const float*)d_in[0];
  const float* qkv_w      = (const float*)d_in[1];
  const float* qkv_b      = (const float*)d_in[2];
  const float* out_w      = (const float*)d_in[3];
  const float* out_b      = (const float*)d_in[4];
  const float* bias_table = (const float*)d_in[5];
  const int*   rel_idx    = (const int*)d_in[6];
  float* out = (float*)d_out;

  unsigned short* wqkv = (unsigned short*)d_ws;                      // 98,304 B
  unsigned short* wout = wqkv + 3 * CDIM * CDIM;                     // 32,768 B
  float* biasf = (float*)((char*)d_ws + 131072);                     // 65,536 B

  swin_prep<<<192, 256, 0, stream>>>(qkv_w, out_w, bias_table, rel_idx, wqkv, wout, biasf);
  swin_fused<<<NWIN / 4, 256, 0, stream>>>(x, wqkv, qkv_b, wout, out_b, biasf, out);
}